// Round 6
// baseline (116.115 us; speedup 1.0000x reference)
//
#include <hip/hip_runtime.h>
#include <hip/hip_bf16.h>
#include <stdint.h>

#define B_SZ 1024
#define M_SZ 209
#define MPAD 256            // padded M rows (8 * 32)
#define D_SZ 12288
#define KC   48             // split-K chunks; grid (48,16) = 768 blocks = 3/CU
#define KCH  (D_SZ / KC)    // 256
#define BK   64             // K per staging iteration
#define NIT  (KCH / BK)     // 4
#define NB   16             // B splits
#define BT   64             // B rows per block (2 row-tiles of 32)
#define SROW 224            // slab k-stride in elems (cols 224..255 are zero-pad, skipped)
#define SLROW (KC * SROW)   // 10752

// ws byte offsets
#define CBF_OFF  0u                                   // c bf16 [256][12288]
#define XXP_OFF  (MPAD * D_SZ * 2)                    // xx partials [B][KC] f32
#define CCP_OFF  (XXP_OFF + B_SZ * KC * 4)            // cc halves [256][2] f32
#define SLAB_OFF (CCP_OFF + MPAD * 2 * 4)             // slab [B][KC][224] bf16 (~22 MB)

typedef __attribute__((ext_vector_type(8)))  short short8;
typedef __attribute__((ext_vector_type(16))) float floatx16;

__device__ __forceinline__ uint32_t pk2(float lo, float hi) {
    union { __hip_bfloat162 h; uint32_t u; } cv;
    cv.h = __float22bfloat162_rn(float2{lo, hi});
    return cv.u;
}

__device__ __forceinline__ float bfbits2f(unsigned short u) {
    union { uint32_t u; float f; } cv;
    cv.u = ((uint32_t)u) << 16;
    return cv.f;
}

__device__ __forceinline__ void gload_lds16(const void* g, void* l) {
    __builtin_amdgcn_global_load_lds(
        (const __attribute__((address_space(1))) void*)g,
        (__attribute__((address_space(3))) void*)l, 16, 0, 0);
}

// ---------------------------------------------------------------------------
// prepass: c fp32 -> bf16 (padded to 256 rows, zeros) + ||c||^2 halves.
// 2 blocks per row (512 blocks), no atomics: ccp[j][h] per half.
__global__ __launch_bounds__(256) void rbf_prep(
    const float* __restrict__ c, unsigned short* __restrict__ cbf,
    float* __restrict__ ccp)
{
    __shared__ float red[4];
    const int j = blockIdx.x >> 1, h = blockIdx.x & 1;
    const int t = threadIdx.x;
    const int base = h * (D_SZ / 2);
    unsigned short* dst = cbf + (size_t)j * D_SZ + base;
    float s = 0.f;
    if (j < M_SZ) {
        const float* src = c + (size_t)j * D_SZ + base;
        for (int i = t * 8; i < D_SZ / 2; i += 2048) {
            float4 v0 = *(const float4*)(src + i);
            float4 v1 = *(const float4*)(src + i + 4);
            s += v0.x*v0.x + v0.y*v0.y + v0.z*v0.z + v0.w*v0.w
               + v1.x*v1.x + v1.y*v1.y + v1.z*v1.z + v1.w*v1.w;
            uint4 w = { pk2(v0.x,v0.y), pk2(v0.z,v0.w), pk2(v1.x,v1.y), pk2(v1.z,v1.w) };
            *(uint4*)(dst + i) = w;
        }
    } else {
        uint4 zz = {0u, 0u, 0u, 0u};
        for (int i = t * 8; i < D_SZ / 2; i += 2048) *(uint4*)(dst + i) = zz;
    }
#pragma unroll
    for (int off = 32; off > 0; off >>= 1) s += __shfl_down(s, off);
    if ((t & 63) == 0) red[t >> 6] = s;
    __syncthreads();
    if (t == 0) ccp[j * 2 + h] = red[0] + red[1] + red[2] + red[3];
}

// ---------------------------------------------------------------------------
// main: split-K distance GEMM, 32x32x16 bf16 MFMA, 2x2 wave tiling.
// c via global_load_lds DMA (XOR-swizzled LDS); all x prefetched in prologue.
__global__ __launch_bounds__(256, 3) void rbf_main(
    const float* __restrict__ x, const unsigned short* __restrict__ cbf,
    __hip_bfloat16* __restrict__ slab, float* __restrict__ xxp)
{
    __shared__ unsigned short sx[BT * BK];    //  8 KB
    __shared__ unsigned short sc[MPAD * BK];  // 32 KB

    const int t    = threadIdx.x;
    const int k    = blockIdx.x;
    const int b    = blockIdx.y;
    const int wave = t >> 6, lane = t & 63;
    const int n = lane & 31, h = lane >> 5, e = lane & 7;
    const int rowtile = wave & 1;            // which 32-row half of the B-tile
    const int ctbase  = (wave >> 1) * 4;     // which 4 of the 8 32-col c-tiles

    floatx16 acc[4];
#pragma unroll
    for (int i = 0; i < 4; ++i)
#pragma unroll
        for (int r2 = 0; r2 < 16; ++r2) acc[i][r2] = 0.f;

    // ---- prologue: prefetch + convert ALL x for this block's k-slice
    const int r  = t >> 2;
    const int c0 = (t & 3) * 2;
    const float* xp = x + (size_t)(b * BT + r) * D_SZ + (size_t)k * KCH + (t & 3) * 16;

    uint4 xw[NIT][2];
    float sxx = 0.f;
#pragma unroll
    for (int it = 0; it < NIT; ++it) {
        float4 v0 = *(const float4*)(xp + it * BK + 0);
        float4 v1 = *(const float4*)(xp + it * BK + 4);
        float4 v2 = *(const float4*)(xp + it * BK + 8);
        float4 v3 = *(const float4*)(xp + it * BK + 12);
        sxx += v0.x*v0.x + v0.y*v0.y + v0.z*v0.z + v0.w*v0.w
             + v1.x*v1.x + v1.y*v1.y + v1.z*v1.z + v1.w*v1.w
             + v2.x*v2.x + v2.y*v2.y + v2.z*v2.z + v2.w*v2.w
             + v3.x*v3.x + v3.y*v3.y + v3.z*v3.z + v3.w*v3.w;
        xw[it][0] = make_uint4(pk2(v0.x,v0.y), pk2(v0.z,v0.w), pk2(v1.x,v1.y), pk2(v1.z,v1.w));
        xw[it][1] = make_uint4(pk2(v2.x,v2.y), pk2(v2.z,v2.w), pk2(v3.x,v3.y), pk2(v3.z,v3.w));
    }
    unsigned short* xw0 = &sx[r * BK + ((c0    ) ^ (r & 7)) * 8];
    unsigned short* xw1 = &sx[r * BK + ((c0 + 1) ^ (r & 7)) * 8];

    // c DMA: lane L of round cr -> row cr*8 + L/8, LDS chunk L%8,
    // source chunk (L%8) ^ (row&7)
    const int lr8 = lane >> 3, lc8 = lane & 7;
    const unsigned short* cpb = cbf + (size_t)lr8 * D_SZ + (size_t)k * KCH
                              + (size_t)((lc8 ^ lr8) * 8);

    // fragment bases (LDS chunk q at row rr holds source chunk q ^ (rr&7);
    // rr&7 == e for both A rows (rowtile*32+n) and B rows (ct*32+n))
    const unsigned short* abase = &sx[(rowtile * 32 + n) * BK];
    const unsigned short* bbase = &sc[n * BK];

    for (int it = 0; it < NIT; ++it) {
        // c tile: 32 DMA rounds of 8 rows (8 per wave), 1 KB each
#pragma unroll
        for (int jj = 0; jj < 8; ++jj) {
            const int cr = wave * 8 + jj;
            gload_lds16(cpb + (size_t)cr * 8 * D_SZ + it * BK, &sc[cr * 512]);
        }
        *(uint4*)xw0 = xw[it][0];
        *(uint4*)xw1 = xw[it][1];
        __syncthreads();

        // 4 k-steps of 16 over this BK=64 slab
#pragma unroll
        for (int ks = 0; ks < 4; ++ks) {
            const int ch = (((2 * ks + h) ^ e)) * 8;   // swizzled chunk offset
            short8 a = *(const short8*)(abase + ch);
#pragma unroll
            for (int cc2 = 0; cc2 < 4; ++cc2) {
                short8 bf = *(const short8*)(bbase + (ctbase + cc2) * 32 * BK + ch);
                acc[cc2] = __builtin_amdgcn_mfma_f32_32x32x16_bf16(a, bf, acc[cc2], 0, 0, 0);
            }
        }
        __syncthreads();
    }

    // ---- slab write: [i][k][224] bf16.
    // C/D layout (32x32): col = lane&31, row = (reg&3) + 8*(reg>>2) + 4*(lane>>5)
    __hip_bfloat16* sd = slab + (size_t)k * SROW;
    const int gib = b * BT + rowtile * 32 + 4 * h;
#pragma unroll
    for (int cc2 = 0; cc2 < 4; ++cc2) {
        const int gj = (ctbase + cc2) * 32 + n;
        if (gj < SROW) {
#pragma unroll
            for (int reg = 0; reg < 16; ++reg) {
                const int gi = gib + (reg & 3) + 8 * (reg >> 2);
                sd[(size_t)gi * SLROW + gj] = __float2bfloat16(acc[cc2][reg]);
            }
        }
    }

    // ---- xx partials (no atomics)
    sxx += __shfl_down(sxx, 2);
    sxx += __shfl_down(sxx, 1);
    if ((t & 3) == 0) xxp[(size_t)(b * BT + r) * KC + k] = sxx;
}

// ---------------------------------------------------------------------------
// finalize: one block per row; thread t = column j. Reduce 48 k-partials,
// d2 = xx + cc - 2*dot, radial = exp(-sqrt/sig^2), dot with W, block-reduce.
__global__ __launch_bounds__(256) void rbf_fin(
    const __hip_bfloat16* __restrict__ slab, const float* __restrict__ xxp,
    const float* __restrict__ ccp, const float* __restrict__ sigma,
    const float* __restrict__ W, const float* __restrict__ bias,
    float* __restrict__ out)
{
    __shared__ float xsh;
    __shared__ float red[8];

    const int t = threadIdx.x;
    const int i = blockIdx.x;
    const int wave = t >> 6, lane = t & 63;

    // dot reduction over k (coalesced: per kk, 224 threads read 448 B contiguous)
    float s = 0.f;
    if (t < SROW) {
        const unsigned short* sp = (const unsigned short*)slab + (size_t)i * SLROW + t;
#pragma unroll 8
        for (int kk = 0; kk < KC; ++kk) s += bfbits2f(sp[kk * SROW]);
    }

    // xx reduction (wave 0)
    if (t < 64) {
        float xv = (t < KC) ? xxp[(size_t)i * KC + t] : 0.f;
#pragma unroll
        for (int off = 32; off > 0; off >>= 1) xv += __shfl_down(xv, off);
        if (t == 0) xsh = xv;
    }
    __syncthreads();

    float a0 = 0.f, a1 = 0.f;
    if (t < M_SZ) {
        const float ccj = ccp[t * 2] + ccp[t * 2 + 1];
        float d2 = fmaxf(xsh + ccj - 2.f * s, 0.f);
        float sg = sigma[t];
        float rad = __expf(-sqrtf(d2) / (sg * sg));
        a0 = rad * W[t];
        a1 = rad * W[M_SZ + t];
    }
#pragma unroll
    for (int off = 32; off > 0; off >>= 1) {
        a0 += __shfl_down(a0, off);
        a1 += __shfl_down(a1, off);
    }
    if (lane == 0) { red[wave * 2] = a0; red[wave * 2 + 1] = a1; }
    __syncthreads();
    if (t == 0) out[i * 2 + 0] = red[0] + red[2] + red[4] + red[6] + bias[0];
    if (t == 1) out[i * 2 + 1] = red[1] + red[3] + red[5] + red[7] + bias[1];
}

// ---------------------------------------------------------------------------
extern "C" void kernel_launch(void* const* d_in, const int* in_sizes, int n_in,
                              void* d_out, int out_size, void* d_ws, size_t ws_size,
                              hipStream_t stream)
{
    const float* x     = (const float*)d_in[0];
    const float* c     = (const float*)d_in[1];
    const float* sigma = (const float*)d_in[2];
    const float* W     = (const float*)d_in[3];
    const float* bias  = (const float*)d_in[4];
    float* out = (float*)d_out;

    char* ws = (char*)d_ws;
    unsigned short*  cbf  = (unsigned short*)(ws + CBF_OFF);
    float*           xxp  = (float*)(ws + XXP_OFF);
    float*           ccp  = (float*)(ws + CCP_OFF);
    __hip_bfloat16*  slab = (__hip_bfloat16*)(ws + SLAB_OFF);

    rbf_prep<<<MPAD * 2, 256, 0, stream>>>(c, cbf, ccp);
    rbf_main<<<dim3(KC, NB), 256, 0, stream>>>(x, cbf, slab, xxp);
    rbf_fin<<<B_SZ, 256, 0, stream>>>(slab, xxp, ccp, sigma, W, bias, out);
}